// Round 14
// baseline (5299.917 us; speedup 1.0000x reference)
//
#include <hip/hip_runtime.h>
#include <math.h>

#define T_LEN 8192

typedef float f32x4 __attribute__((ext_vector_type(4)));
typedef int   i32x8 __attribute__((ext_vector_type(8)));
typedef int   i32x6 __attribute__((ext_vector_type(6)));   // fp6 operand tuple

#define DPP_MAX(x, ctrl) fmaxf((x), __int_as_float(__builtin_amdgcn_update_dpp(0, __float_as_int(x), (ctrl), 0xF, 0xF, true)))
#define SB() __builtin_amdgcn_sched_barrier(0)

// LDS-only barrier: drain LDS ops, leave global loads/stores in flight.
#define BAR_LDS() do { \
    __builtin_amdgcn_sched_barrier(0); \
    asm volatile("s_waitcnt lgkmcnt(0)" ::: "memory"); \
    __builtin_amdgcn_s_barrier(); \
    __builtin_amdgcn_sched_barrier(0); \
} while (0)

__device__ __forceinline__ float fexp2(float x) {
#if __has_builtin(__builtin_amdgcn_exp2f)
    return __builtin_amdgcn_exp2f(x);
#else
    return exp2f(x);
#endif
}
__device__ __forceinline__ float rcp1p(float e) {
    return __builtin_amdgcn_rcpf(1.f + e);
}
__device__ __forceinline__ float fsig_c(float x) {
    x = fminf(30.f, fmaxf(-30.f, x));
    float e = __expf(-x);
    return __builtin_amdgcn_rcpf(1.f + e);
}
__device__ __forceinline__ float ftanh_c(float x) {
    x = fminf(15.f, fmaxf(-15.f, x));
    float e = __expf(-2.f * x);
    return (1.f - e) * __builtin_amdgcn_rcpf(1.f + e);
}

// ---- OCP e4m3fn encode ----
__device__ __forceinline__ unsigned char enc_e4m3(float x) {
#if __has_builtin(__builtin_amdgcn_cvt_pk_fp8_f32)
    int v = __builtin_amdgcn_cvt_pk_fp8_f32(x, 0.f, 0, false);
    return (unsigned char)(v & 0xff);
#else
    unsigned u = __float_as_uint(x);
    unsigned s = (u >> 24) & 0x80u;
    float a = fabsf(x);
    if (a > 448.f) a = 448.f;
    if (a < 9.765625e-4f) return (unsigned char)s;
    int e = ((int)((__float_as_uint(a) >> 23) & 0xffu)) - 127;
    int eu = e < -6 ? -6 : e;
    float ulp = exp2f((float)(eu - 3));
    float q = rintf(a / ulp);
    int mant, ee;
    if (eu == -6 && q < 8.f) { mant = (int)q; ee = 0; }
    else {
        if (q >= 16.f) { q *= 0.5f; eu += 1; }
        mant = (int)q - 8; ee = eu + 7;
        if (ee > 15 || (ee == 15 && mant > 6)) { ee = 15; mant = 6; }
    }
    return (unsigned char)(s | (unsigned)(ee << 3) | (unsigned)mant);
#endif
}
__device__ __forceinline__ unsigned pk4(float a, float b, float c, float d) {
    return (unsigned)enc_e4m3(a) | ((unsigned)enc_e4m3(b) << 8)
         | ((unsigned)enc_e4m3(c) << 16) | ((unsigned)enc_e4m3(d) << 24);
}

// ---- OCP e2m3 (fp6) encode: full version (pre-pass only) ----
__device__ __forceinline__ unsigned enc_e2m3(float x) {
    unsigned s = (__float_as_uint(x) >> 31) << 5;
    float a = fabsf(x);
    a = fminf(a, 7.5f);
    if (a < 0.0625f) return s;
    int e = ((int)((__float_as_uint(a) >> 23) & 0xffu)) - 127;
    int eu = e < 0 ? 0 : e;
    float ulp = __int_as_float((unsigned)(eu + 124) << 23);     // 2^(eu-3)
    float q = rintf(a * __builtin_amdgcn_rcpf(ulp));
    int E, M;
    if (e < 0) {
        if (q >= 8.f) { E = 1; M = 0; }
        else { E = 0; M = (int)q; }
    } else {
        if (q >= 16.f) { q = 8.f; eu += 1; }
        if (eu > 2) { E = 3; M = 7; }
        else { E = eu + 1; M = (int)q - 8; }
    }
    return s | (unsigned)(E << 3) | (unsigned)M;
}

// ---- fast e2m3 for |h|<1 (a=4|h|<4): piecewise-linear, bit-identical ----
__device__ __forceinline__ int enc_e2m3_h4(float h) {
    float x = h * 4.f;
    float a = fabsf(x);
    int c1 = (int)rintf(a * 8.f);
    int c2 = (int)rintf(a * 4.f) + 8;
    int mag = (a < 2.f) ? c1 : c2;
    return mag | (int)((__float_as_uint(h) >> 26) & 32u);
}

// ---------------------------------------------------------------------------
// Kernel 0: pre-pass pack for the DPP-quad layout.
// Tile gt=16w+rt, tile-row rw=4kg+g  <->  W_hh row g*256 + 64*(gt>>4) + (gt&15) + 16kg.
// ---------------------------------------------------------------------------
__global__ __launch_bounds__(256) void pack_w6b(
    const float* __restrict__ w_hh,   // (1024, 256)
    unsigned* __restrict__ w6)        // 8192 items x 8 dwords (6 used)
{
    int idx = blockIdx.x * 256 + threadIdx.x;   // 0..8191
    int l  = idx & 63;
    int kt = (idx >> 6) & 1;
    int gt = idx >> 7;                            // 0..63
    int rw = l & 15, ks = l >> 4;
    int orow = ((rw & 3) << 8) + 64 * (gt >> 4) + (gt & 15) + 16 * (rw >> 2);
    const float* s = w_hh + (size_t)orow * 256 + 128 * kt + 32 * ks;
    unsigned d[6] = {0, 0, 0, 0, 0, 0};
#pragma unroll
    for (int j = 0; j < 32; ++j) {
        unsigned c = enc_e2m3(s[j] * 32.f);
        int bit = 6 * j;
        d[bit >> 5] |= c << (bit & 31);
        if ((bit & 31) > 26) d[(bit >> 5) + 1] |= c >> (32 - (bit & 31));
    }
    unsigned* o = w6 + (size_t)idx * 8;
    o[0] = d[0]; o[1] = d[1]; o[2] = d[2];
    o[3] = d[3]; o[4] = d[4]; o[5] = d[5];
    o[6] = 0;    o[7] = 0;
}

// ---------------------------------------------------------------------------
// Kernel 1: pre = relu(embed_W[docs]) @ w_ih^T + (b_ih + b_hh)   (T x 1024)
// Output columns PERMUTED: col' = 4*unit + gate
// ---------------------------------------------------------------------------
__global__ __launch_bounds__(256, 4) void gemm_pre(
    const int* __restrict__ docs,
    const float* __restrict__ embW,
    const float* __restrict__ w_ih,
    const float* __restrict__ b_ih,
    const float* __restrict__ b_hh,
    float* __restrict__ pre)
{
    __shared__ __align__(16) float As[16][68];
    __shared__ __align__(16) float Bs[16][68];
    __shared__ int rowid[64];
    const int bt = blockIdx.x;
    const int bj = blockIdx.y;
    const int tid = threadIdx.x;
    if (tid < 64) rowid[tid] = docs[bt * 64 + tid];
    __syncthreads();
    const int ti = tid & 15, tj = tid >> 4;
    const int r = tid & 63;
    const int kk4 = (tid >> 6) * 4;
    float acc[4][4];
#pragma unroll
    for (int ii = 0; ii < 4; ++ii)
#pragma unroll
        for (int jj = 0; jj < 4; ++jj) acc[ii][jj] = 0.f;

    for (int k0 = 0; k0 < 256; k0 += 16) {
        float4 av = *(const float4*)(embW + (size_t)rowid[r] * 256 + k0 + kk4);
        float4 bv = *(const float4*)(w_ih + (size_t)(bj * 64 + r) * 256 + k0 + kk4);
        As[kk4 + 0][r] = fmaxf(av.x, 0.f);
        As[kk4 + 1][r] = fmaxf(av.y, 0.f);
        As[kk4 + 2][r] = fmaxf(av.z, 0.f);
        As[kk4 + 3][r] = fmaxf(av.w, 0.f);
        Bs[kk4 + 0][r] = bv.x;
        Bs[kk4 + 1][r] = bv.y;
        Bs[kk4 + 2][r] = bv.z;
        Bs[kk4 + 3][r] = bv.w;
        __syncthreads();
#pragma unroll
        for (int kk = 0; kk < 16; ++kk) {
            float4 a = *(const float4*)&As[kk][ti * 4];
            float4 b = *(const float4*)&Bs[kk][tj * 4];
            acc[0][0] += a.x * b.x; acc[0][1] += a.x * b.y; acc[0][2] += a.x * b.z; acc[0][3] += a.x * b.w;
            acc[1][0] += a.y * b.x; acc[1][1] += a.y * b.y; acc[1][2] += a.y * b.z; acc[1][3] += a.y * b.w;
            acc[2][0] += a.z * b.x; acc[2][1] += a.z * b.y; acc[2][2] += a.z * b.z; acc[2][3] += a.z * b.w;
            acc[3][0] += a.w * b.x; acc[3][1] += a.w * b.y; acc[3][2] += a.w * b.z; acc[3][3] += a.w * b.w;
        }
        __syncthreads();
    }
#pragma unroll
    for (int ii = 0; ii < 4; ++ii) {
        int t = bt * 64 + ti * 4 + ii;
#pragma unroll
        for (int jj = 0; jj < 4; ++jj) {
            int j = bj * 64 + tj * 4 + jj;
            int jp = ((j & 255) << 2) | (j >> 8);
            pre[(size_t)t * 1024 + jp] = acc[ii][jj] + b_ih[j] + b_hh[j];
        }
    }
}

// fp6 MFMA, A from AGPRs. K0: C = pinned zero (independent). K1: C = D (acc).
#define MFMA_K0(RT, DST) \
    asm("v_mfma_scale_f32_16x16x128_f8f6f4 %0, %1, %2, %3, %4, %4 cbsz:2 blgp:2" \
        : "=&v"(DST) : "a"(wA[RT][0]), "v"(bq0), "v"(CZ), "v"(sc))
#define MFMA_K1(RT, DST) \
    asm("v_mfma_scale_f32_16x16x128_f8f6f4 %0, %1, %2, %0, %3, %3 cbsz:2 blgp:2" \
        : "+v"(DST) : "a"(wA[RT][1]), "v"(bq1), "v"(sc))

// legacy dependent pair (fallback kernel mx6b)
#define MFMA_PAIR(RT, DST) \
    asm("v_mfma_scale_f32_16x16x128_f8f6f4 %0, %1, %2, %5, %6, %6 cbsz:2 blgp:2\n\t" \
        "v_mfma_scale_f32_16x16x128_f8f6f4 %0, %3, %4, %0, %6, %6 cbsz:2 blgp:2" \
        : "=&v"(DST) \
        : "a"(wA[RT][0]), "v"(bq0), "a"(wA[RT][1]), "v"(bq1), "v"(CZ), "v"(sc))

// ---------------------------------------------------------------------------
// Kernel 2a (primary): 4-wave MX-fp6 scan, DEP-BROKEN MFMA schedule.
// Phase 1: 16 independent kt=0 MFMAs (C=0). Phase 2: 16 kt=1 MFMAs, each
// reading its kt0 result as C (16 insts away - pipeline-covered). Selects
// woven >=4 MFMAs behind producers. Numerics identical to r13.
// ---------------------------------------------------------------------------
__global__ __launch_bounds__(256, 1) void lstm_scan_mx6c(
    const float* __restrict__ pre,    // (T, 1024), permuted cols 4u+gate
    const unsigned* __restrict__ w6,  // packed fp6 weights (pack_w6b layout)
    float* __restrict__ hs)           // (T, 256) fp32
{
    const int tid = threadIdx.x;
    const int w  = tid >> 6;          // wave 0..3
    const int l  = tid & 63;
    const int rto = l & 15;           // owned tile = column
    const int kgr = l >> 4;           // B k-slice / row-block
    const float C_L2E  = -1.4426950408889634f;
    const float C_L2E2 = -2.8853900817779268f;
    const float I_L2E  = C_L2E  / 128.f;
    const float I_L2E2 = C_L2E2 / 128.f;

    __shared__ __align__(32) unsigned char h6pk[2][256];  // 8 windows x 32B

    i32x6 wA[16][2];
#pragma unroll
    for (int rtt = 0; rtt < 16; ++rtt) {
#pragma unroll
        for (int kt = 0; kt < 2; ++kt) {
            int gt = 16 * w + rtt;
            const unsigned* s = w6 + (size_t)((gt * 2 + kt) * 64 + l) * 8;
            uint4 lo = *(const uint4*)s;
            uint2 hi = *(const uint2*)(s + 4);
            i32x6 v;
            v[0] = (int)lo.x; v[1] = (int)lo.y; v[2] = (int)lo.z;
            v[3] = (int)lo.w; v[4] = (int)hi.x; v[5] = (int)hi.y;
            wA[rtt][kt] = v;
        }
    }

    for (int i = tid; i < 512; i += 256) ((unsigned char*)h6pk)[i] = 0;

    const int u = 64 * w + rto + 16 * kgr;                // owned unit
    float c_st = 0.f;

    const bool b0 = (rto & 1), b1 = (rto & 2), b2 = (rto & 4), b3 = (rto & 8);

    // DPP-quad pack constants: quad q = l>>2, G = 4*(q>>2) + (q&3)
    const int qi  = l & 3;
    const bool iswr = (qi < 3);
    const int rsh = 2 * qi;
    const int qq  = l >> 2;
    const int G   = 4 * (qq >> 2) + (qq & 3);
    const int wofs = (2 * w + (G >> 3)) * 32 + 3 * (G & 7) + qi;

    f32x4 CZ = (f32x4){0.f, 0.f, 0.f, 0.f};
    asm("" : "+v"(CZ));                                   // pin zero tuple
    int sc = 0x7f7f7f7f;                                  // e8m0 scale = 1.0

    f32x4 p4c = *(const f32x4*)(pre + 4 * u);             // t = 0
    float tx = p4c.x * C_L2E;
    float ty = p4c.y * C_L2E;
    float tz = p4c.z * C_L2E2;
    float tw = p4c.w * C_L2E;
    const float* pp = pre + 1024 + 4 * u;
    float* hsp = hs + u;
    const unsigned char* h6base = (const unsigned char*)h6pk;
    BAR_LDS();

#define LSTM_STEP(RD, WR) do { \
    f32x4 p4n = *(const f32x4*)pp; pp += 1024; \
    i32x6 bq0, bq1; \
    { \
        const unsigned char* bp0 = h6base + (RD) + kgr * 32; \
        uint4 lo = *(const uint4*)bp0; \
        uint2 hi = *(const uint2*)(bp0 + 16); \
        bq0[0] = (int)lo.x; bq0[1] = (int)lo.y; bq0[2] = (int)lo.z; \
        bq0[3] = (int)lo.w; bq0[4] = (int)hi.x; bq0[5] = (int)hi.y; \
        const unsigned char* bp1 = bp0 + 128; \
        uint4 lo1 = *(const uint4*)bp1; \
        uint2 hi1 = *(const uint2*)(bp1 + 16); \
        bq1[0] = (int)lo1.x; bq1[1] = (int)lo1.y; bq1[2] = (int)lo1.z; \
        bq1[3] = (int)lo1.w; bq1[4] = (int)hi1.x; bq1[5] = (int)hi1.y; \
    } \
    f32x4 a0, a1, a2, a3, a4, a5, a6, a7, a8, a9, a10, a11, a12, a13, a14, a15; \
    MFMA_K0(0, a0);   MFMA_K0(1, a1);   MFMA_K0(2, a2);   MFMA_K0(3, a3); \
    MFMA_K0(4, a4);   MFMA_K0(5, a5);   MFMA_K0(6, a6);   MFMA_K0(7, a7); \
    MFMA_K0(8, a8);   MFMA_K0(9, a9);   MFMA_K0(10, a10); MFMA_K0(11, a11); \
    MFMA_K0(12, a12); MFMA_K0(13, a13); MFMA_K0(14, a14); MFMA_K0(15, a15); \
    SB(); \
    MFMA_K1(0, a0);   MFMA_K1(1, a1);   MFMA_K1(2, a2);   MFMA_K1(3, a3); \
    MFMA_K1(4, a4);   MFMA_K1(5, a5);   SB(); \
    f32x4 s0 = b0 ? a1 : a0; \
    MFMA_K1(6, a6);   MFMA_K1(7, a7);   SB(); \
    f32x4 s1 = b0 ? a3 : a2; \
    MFMA_K1(8, a8);   MFMA_K1(9, a9);   SB(); \
    f32x4 s2 = b0 ? a5 : a4; \
    f32x4 q0 = b1 ? s1 : s0; \
    MFMA_K1(10, a10); MFMA_K1(11, a11); SB(); \
    f32x4 s3 = b0 ? a7 : a6; \
    MFMA_K1(12, a12); MFMA_K1(13, a13); SB(); \
    f32x4 s4 = b0 ? a9 : a8; \
    MFMA_K1(14, a14); MFMA_K1(15, a15); SB(); \
    f32x4 s5 = b0 ? a11 : a10; \
    f32x4 q1 = b1 ? s3 : s2; \
    asm volatile("s_nop 7\n\ts_nop 7\n\ts_nop 7" : "+v"(a12), "+v"(a13), "+v"(a14), "+v"(a15)); \
    f32x4 s6 = b0 ? a13 : a12; \
    f32x4 s7 = b0 ? a15 : a14; \
    f32x4 q2 = b1 ? s5 : s4; \
    f32x4 q3 = b1 ? s7 : s6; \
    f32x4 r0 = b2 ? q1 : q0; \
    f32x4 r1 = b2 ? q3 : q2; \
    f32x4 av = b3 ? r1 : r0; \
    float nx = p4n.x * C_L2E, ny = p4n.y * C_L2E; \
    float nz = p4n.z * C_L2E2, nw = p4n.w * C_L2E; \
    float si = rcp1p(fexp2(fmaf(av.x, I_L2E,  tx))); \
    float sf = rcp1p(fexp2(fmaf(av.y, I_L2E,  ty))); \
    float tg = 2.f * rcp1p(fexp2(fmaf(av.z, I_L2E2, tz))) - 1.f; \
    float so = rcp1p(fexp2(fmaf(av.w, I_L2E,  tw))); \
    c_st = sf * c_st + si * tg; \
    float h = so * (2.f * rcp1p(fexp2(c_st * C_L2E2)) - 1.f); \
    hsp[0] = h; hsp += 256; \
    int code = enc_e2m3_h4(h); \
    int cnx = __builtin_amdgcn_update_dpp(0, code, 0x39, 0xF, 0xF, true); \
    if (iswr) { \
        unsigned byte = (((unsigned)code >> rsh) | ((unsigned)cnx << (6 - rsh))) & 0xffu; \
        *((unsigned char*)h6pk + (WR) + wofs) = (unsigned char)byte; \
    } \
    tx = nx; ty = ny; tz = nz; tw = nw; \
    BAR_LDS(); \
} while (0)

    for (int t2 = 0; t2 < T_LEN; t2 += 2) {
        LSTM_STEP(256, 0);    // even step: read parity 1, write parity 0
        LSTM_STEP(0, 256);    // odd step: read parity 0, write parity 1
    }
#undef LSTM_STEP
}

// ---------------------------------------------------------------------------
// Kernel 2b (fallback 1): r13 proven kernel (dependent pairs), 4848 us.
// ---------------------------------------------------------------------------
__global__ __launch_bounds__(256, 1) void lstm_scan_mx6b(
    const float* __restrict__ pre,
    const unsigned* __restrict__ w6,
    float* __restrict__ hs)
{
    const int tid = threadIdx.x;
    const int w  = tid >> 6;
    const int l  = tid & 63;
    const int rto = l & 15;
    const int kgr = l >> 4;
    const float C_L2E  = -1.4426950408889634f;
    const float C_L2E2 = -2.8853900817779268f;
    const float I_L2E  = C_L2E  / 128.f;
    const float I_L2E2 = C_L2E2 / 128.f;

    __shared__ __align__(32) unsigned char h6pk[2][256];

    i32x6 wA[16][2];
#pragma unroll
    for (int rtt = 0; rtt < 16; ++rtt) {
#pragma unroll
        for (int kt = 0; kt < 2; ++kt) {
            int gt = 16 * w + rtt;
            const unsigned* s = w6 + (size_t)((gt * 2 + kt) * 64 + l) * 8;
            uint4 lo = *(const uint4*)s;
            uint2 hi = *(const uint2*)(s + 4);
            i32x6 v;
            v[0] = (int)lo.x; v[1] = (int)lo.y; v[2] = (int)lo.z;
            v[3] = (int)lo.w; v[4] = (int)hi.x; v[5] = (int)hi.y;
            wA[rtt][kt] = v;
        }
    }

    for (int i = tid; i < 512; i += 256) ((unsigned char*)h6pk)[i] = 0;

    const int u = 64 * w + rto + 16 * kgr;
    float c_st = 0.f;

    const bool b0 = (rto & 1), b1 = (rto & 2), b2 = (rto & 4), b3 = (rto & 8);

    const int qi  = l & 3;
    const bool iswr = (qi < 3);
    const int rsh = 2 * qi;
    const int qq  = l >> 2;
    const int G   = 4 * (qq >> 2) + (qq & 3);
    const int wofs = (2 * w + (G >> 3)) * 32 + 3 * (G & 7) + qi;

    f32x4 CZ = (f32x4){0.f, 0.f, 0.f, 0.f};
    asm("" : "+v"(CZ));
    int sc = 0x7f7f7f7f;

    f32x4 p4c = *(const f32x4*)(pre + 4 * u);
    float tx = p4c.x * C_L2E;
    float ty = p4c.y * C_L2E;
    float tz = p4c.z * C_L2E2;
    float tw = p4c.w * C_L2E;
    const float* pp = pre + 1024 + 4 * u;
    float* hsp = hs + u;
    const unsigned char* h6base = (const unsigned char*)h6pk;
    BAR_LDS();

#define LSTM_STEP(RD, WR) do { \
    f32x4 p4n = *(const f32x4*)pp; pp += 1024; \
    i32x6 bq0, bq1; \
    { \
        const unsigned char* bp0 = h6base + (RD) + kgr * 32; \
        uint4 lo = *(const uint4*)bp0; \
        uint2 hi = *(const uint2*)(bp0 + 16); \
        bq0[0] = (int)lo.x; bq0[1] = (int)lo.y; bq0[2] = (int)lo.z; \
        bq0[3] = (int)lo.w; bq0[4] = (int)hi.x; bq0[5] = (int)hi.y; \
        const unsigned char* bp1 = bp0 + 128; \
        uint4 lo1 = *(const uint4*)bp1; \
        uint2 hi1 = *(const uint2*)(bp1 + 16); \
        bq1[0] = (int)lo1.x; bq1[1] = (int)lo1.y; bq1[2] = (int)lo1.z; \
        bq1[3] = (int)lo1.w; bq1[4] = (int)hi1.x; bq1[5] = (int)hi1.y; \
    } \
    f32x4 a0, a1, a2, a3, a4, a5, a6, a7, a8, a9, a10, a11, a12, a13, a14, a15; \
    MFMA_PAIR(0, a0);  MFMA_PAIR(1, a1);  MFMA_PAIR(2, a2);  MFMA_PAIR(3, a3); \
    SB(); \
    f32x4 s0 = b0 ? a1 : a0; \
    MFMA_PAIR(4, a4);  MFMA_PAIR(5, a5);  SB(); \
    f32x4 s1 = b0 ? a3 : a2; \
    MFMA_PAIR(6, a6);  MFMA_PAIR(7, a7);  SB(); \
    f32x4 s2 = b0 ? a5 : a4; \
    MFMA_PAIR(8, a8);  MFMA_PAIR(9, a9);  SB(); \
    f32x4 s3 = b0 ? a7 : a6; \
    f32x4 q0 = b1 ? s1 : s0; \
    MFMA_PAIR(10, a10); MFMA_PAIR(11, a11); SB(); \
    f32x4 s4 = b0 ? a9 : a8; \
    MFMA_PAIR(12, a12); MFMA_PAIR(13, a13); SB(); \
    f32x4 s5 = b0 ? a11 : a10; \
    f32x4 q1 = b1 ? s3 : s2; \
    MFMA_PAIR(14, a14); MFMA_PAIR(15, a15); SB(); \
    f32x4 s6 = b0 ? a13 : a12; \
    asm volatile("s_nop 7\n\ts_nop 7" : "+v"(a14), "+v"(a15)); \
    f32x4 s7 = b0 ? a15 : a14; \
    f32x4 q2 = b1 ? s5 : s4; \
    f32x4 q3 = b1 ? s7 : s6; \
    f32x4 r0 = b2 ? q1 : q0; \
    f32x4 r1 = b2 ? q3 : q2; \
    f32x4 av = b3 ? r1 : r0; \
    float nx = p4n.x * C_L2E, ny = p4n.y * C_L2E; \
    float nz = p4n.z * C_L2E2, nw = p4n.w * C_L2E; \
    float si = rcp1p(fexp2(fmaf(av.x, I_L2E,  tx))); \
    float sf = rcp1p(fexp2(fmaf(av.y, I_L2E,  ty))); \
    float tg = 2.f * rcp1p(fexp2(fmaf(av.z, I_L2E2, tz))) - 1.f; \
    float so = rcp1p(fexp2(fmaf(av.w, I_L2E,  tw))); \
    c_st = sf * c_st + si * tg; \
    float h = so * (2.f * rcp1p(fexp2(c_st * C_L2E2)) - 1.f); \
    hsp[0] = h; hsp += 256; \
    int code = enc_e2m3_h4(h); \
    int cnx = __builtin_amdgcn_update_dpp(0, code, 0x39, 0xF, 0xF, true); \
    if (iswr) { \
        unsigned byte = (((unsigned)code >> rsh) | ((unsigned)cnx << (6 - rsh))) & 0xffu; \
        *((unsigned char*)h6pk + (WR) + wofs) = (unsigned char)byte; \
    } \
    tx = nx; ty = ny; tz = nz; tw = nw; \
    BAR_LDS(); \
} while (0)

    for (int t2 = 0; t2 < T_LEN; t2 += 2) {
        LSTM_STEP(256, 0);
        LSTM_STEP(0, 256);
    }
#undef LSTM_STEP
}

// ---------------------------------------------------------------------------
// Kernel 2c (fallback 2): round-6 proven MX-fp8 scan.
// ---------------------------------------------------------------------------
__global__ __launch_bounds__(512, 2) void lstm_scan_mx8(
    const float* __restrict__ pre,
    const float* __restrict__ w_hh,
    float* __restrict__ hs)
{
    const int tid = threadIdx.x;
    const int w  = tid >> 6;
    const int l  = tid & 63;
    const int rw = l & 15;
    const int kg = l >> 4;
    const float INV = 1.f / 32768.f;

    __shared__ __align__(16) unsigned char h8[2 * 256];
    __shared__ __align__(16) float ldsPre[2][1024];

    i32x8 wA[8][2];
#pragma unroll
    for (int rt = 0; rt < 8; ++rt) {
#pragma unroll
        for (int kt = 0; kt < 2; ++kt) {
            int rowp = ((8 * w + rt) << 4) + rw;
            int orow = ((rowp & 3) << 8) + (rowp >> 2);
            const float* s = w_hh + (size_t)orow * 256 + 128 * kt + 32 * kg;
            i32x8 v;
#pragma unroll
            for (int d = 0; d < 8; ++d) {
                float4 f = *(const float4*)(s + 4 * d);
                v[d] = (int)pk4(f.x * 512.f, f.y * 512.f, f.z * 512.f, f.w * 512.f);
            }
            wA[rt][kt] = v;
        }
    }

    for (int i = tid; i < 512; i += 512) h8[i] = 0;
    {
        float2 p = *(const float2*)(pre + 2 * tid);
        *(float2*)&ldsPre[0][2 * tid] = p;
    }
    float c_st = 0.f;
    const bool isup = (rw < 8);
    const int u = 32 * w + 4 * (rw & 7) + kg;
    const float* pnext = pre + 1024 + 2 * tid;
    float* hsp = hs + u;
    __syncthreads();

    for (int t = 0; t < T_LEN; ++t) {
        const int PW = t & 1;
        const int PR = PW ^ 1;

        f32x4 p4 = *(const f32x4*)&ldsPre[PW][4 * u];

        float2 pv = *(const float2*)pnext;
        if (t + 2 < T_LEN) pnext += 1024;

        i32x8 bq[2];
#pragma unroll
        for (int kt = 0; kt < 2; ++kt) {
            const unsigned char* bp = &h8[PR * 256 + 128 * kt + 32 * kg];
            uint4 lo = *(const uint4*)bp;
            uint4 hi = *(const uint4*)(bp + 16);
            i32x8 b;
            b[0] = (int)lo.x; b[1] = (int)lo.y; b[2] = (int)lo.z; b[3] = (int)lo.w;
            b[4] = (int)hi.x; b[5] = (int)hi.y; b[6] = (int)hi.z; b[7] = (int)hi.w;
            bq[kt] = b;
        }

        f32x4 acc[8];
#pragma unroll
        for (int rt = 0; rt < 8; ++rt) acc[rt] = (f32x4){0.f, 0.f, 0.f, 0.f};
#pragma unroll
        for (int rt = 0; rt < 8; ++rt)
#pragma unroll
            for (int kt = 0; kt < 2; ++kt)
                acc[rt] = __builtin_amdgcn_mfma_scale_f32_16x16x128_f8f6f4(
                    wA[rt][kt], bq[kt], acc[rt],
                    0, 0, 0, 0x7f7f7f7f, 0, 0x7f7f7f7f);

        if (isup) {
            f32x4 av = acc[0];
            av = (rw == 1) ? acc[1] : av;
            av = (rw == 2) ? acc[2] : av;
            av = (rw == 3) ? acc[3] : av;
            av = (rw == 4) ? acc[4] : av;
            av = (rw == 5) ? acc[5] : av;
            av = (rw == 6) ? acc[6] : av;
            av = (rw == 7) ? acc[7] : av;
            float gi = fmaf(av.x, INV, p4.x);
            float gf = fmaf(av.y, INV, p4.y);
            float gg = fmaf(av.z, INV, p4.z);
            float go = fmaf(av.w, INV, p4.w);
            float si = fsig_c(gi);
            float sf = fsig_c(gf);
            float tg = ftanh_c(gg);
            float so = fsig_c(go);
            c_st = sf * c_st + si * tg;
            float h = so * ftanh_c(c_st);
            hsp[0] = h;
            h8[PW * 256 + u] = enc_e4m3(h * 64.f);
        }
        hsp += 256;

        *(float2*)&ldsPre[PR][2 * tid] = pv;

        __syncthreads();
    }
}

// ---------------------------------------------------------------------------
// Kernel 3: conv (FN=128, FL=5) over hs + per-block max over its 64 t's.
// ---------------------------------------------------------------------------
__global__ __launch_bounds__(256) void conv_pool(
    const float* __restrict__ hs,
    const float* __restrict__ cw,
    const float* __restrict__ cb,
    float* __restrict__ part)
{
    __shared__ __align__(16) float hst[68 * 260];
    __shared__ __align__(16) float cwS[128 * 68];
    const int blk = blockIdx.x;
    const int t0 = blk * 64;
    const int tid = threadIdx.x;
    const int i = tid & 15;
    const int g = tid >> 4;

    for (int e = tid; e < 68 * 64; e += 256) {
        int rr = e >> 6;
        int c4 = (e & 63) * 4;
        int tg = t0 + rr; if (tg > 8191) tg = 8191;
        float4 v = *(const float4*)(hs + (size_t)tg * 256 + c4);
        *(float4*)&hst[rr * 260 + c4] = v;
    }

    float acc[4][8];
#pragma unroll
    for (int tt = 0; tt < 4; ++tt)
#pragma unroll
        for (int j = 0; j < 8; ++j) acc[tt][j] = 0.f;

    for (int l = 0; l < 5; ++l) {
        for (int hc = 0; hc < 4; ++hc) {
            __syncthreads();
            {
                int n = tid >> 1;
                int hb = (tid & 1) * 32;
                const float* src = cw + (size_t)n * 1280 + l * 256 + hc * 64 + hb;
                float* dst = &cwS[n * 68 + hb];
#pragma unroll
                for (int q = 0; q < 8; ++q) {
                    float4 v = *(const float4*)(src + 4 * q);
                    *(float4*)(dst + 4 * q) = v;
                }
            }
            __syncthreads();
#pragma unroll 4
            for (int q = 0; q < 16; ++q) {
                float4 hvv[4];
#pragma unroll
                for (int tt = 0; tt < 4; ++tt)
                    hvv[tt] = *(const float4*)&hst[(i + 16 * tt + l) * 260 + hc * 64 + 4 * q];
#pragma unroll
                for (int j = 0; j < 8; ++j) {
                    float4 wv = *(const float4*)&cwS[(g + 16 * j) * 68 + 4 * q];
#pragma unroll
                    for (int tt = 0; tt < 4; ++tt) {
                        acc[tt][j] += hvv[tt].x * wv.x + hvv[tt].y * wv.y
                                    + hvv[tt].z * wv.z + hvv[tt].w * wv.w;
                    }
                }
            }
        }
    }

    float m[8];
#pragma unroll
    for (int j = 0; j < 8; ++j) {
        int n = g + 16 * j;
        float cbn = cb[n];
        float mm = -INFINITY;
#pragma unroll
        for (int tt = 0; tt < 4; ++tt) {
            int t = t0 + i + 16 * tt;
            float v = acc[tt][j] + cbn;
            if (t < 8188) mm = fmaxf(mm, v);
        }
        mm = DPP_MAX(mm, 0xB1);
        mm = DPP_MAX(mm, 0x4E);
        mm = DPP_MAX(mm, 0x141);
        mm = DPP_MAX(mm, 0x140);
        m[j] = mm;
    }
    if (i == 0) {
#pragma unroll
        for (int j = 0; j < 8; ++j)
            part[(size_t)blk * 128 + g + 16 * j] = m[j];
    }
}

// ---------------------------------------------------------------------------
// Kernel 4: final head — pool-reduce, logits, log_softmax, loss + acc.
// ---------------------------------------------------------------------------
__global__ void final_head(
    const float* __restrict__ part,
    const float* __restrict__ logits_w,
    const float* __restrict__ logits_b,
    const int* __restrict__ labels,
    float* __restrict__ out)
{
    __shared__ float pooled[128];
    __shared__ float lgt[20];
    int tid = threadIdx.x;
    float mx = -INFINITY;
    for (int b = 0; b < 128; ++b) mx = fmaxf(mx, part[(size_t)b * 128 + tid]);
    pooled[tid] = mx;
    __syncthreads();
    if (tid < 20) {
        float s = logits_b[tid];
        for (int k = 0; k < 128; ++k) s += logits_w[tid * 128 + k] * pooled[k];
        lgt[tid] = s;
    }
    __syncthreads();
    if (tid == 0) {
        float m = lgt[0]; int am = 0;
        for (int c2 = 1; c2 < 20; ++c2) { if (lgt[c2] > m) { m = lgt[c2]; am = c2; } }
        float se = 0.f;
        for (int c2 = 0; c2 < 20; ++c2) se += expf(lgt[c2] - m);
        float lse = m + logf(se);
        int lbl = labels[0];
        out[0] = -(lgt[lbl] - lse);
        out[1] = (am == lbl) ? 1.f : 0.f;
    }
}

// ---------------------------------------------------------------------------
extern "C" void kernel_launch(void* const* d_in, const int* in_sizes, int n_in,
                              void* d_out, int out_size, void* d_ws, size_t ws_size,
                              hipStream_t stream) {
    (void)in_sizes; (void)n_in; (void)out_size;
    const int*   docs   = (const int*)d_in[0];
    const int*   labels = (const int*)d_in[2];
    const float* embW   = (const float*)d_in[4];
    const float* w_ih   = (const float*)d_in[5];
    const float* w_hh   = (const float*)d_in[6];
    const float* b_ih   = (const float*)d_in[7];
    const float* b_hh   = (const float*)d_in[8];
    const float* cw     = (const float*)d_in[9];
    const float* cb     = (const float*)d_in[10];
    const float* lw     = (const float*)d_in[11];
    const float* lb     = (const float*)d_in[12];
    float* out = (float*)d_out;

    char* ws = (char*)d_ws;
    float*    pre  = (float*)(ws);                 // 33554432 B
    float*    hs   = (float*)(ws + 33554432);      //  8388608 B
    float*    part = (float*)(ws + 41943040);      //    65536 B
    unsigned* w6   = (unsigned*)(ws + 42008576);   //   262144 B

    bool ws_ok = (ws_size >= (size_t)42270720);
    hipFuncAttributes aC, aB;
    bool okC = ws_ok
        && (hipFuncGetAttributes(&aC, (const void*)lstm_scan_mx6c) == hipSuccess)
        && (aC.localSizeBytes == 0);
    bool okB = ws_ok
        && (hipFuncGetAttributes(&aB, (const void*)lstm_scan_mx6b) == hipSuccess)
        && (aB.localSizeBytes == 0);

    gemm_pre<<<dim3(128, 16, 1), 256, 0, stream>>>(docs, embW, w_ih, b_ih, b_hh, pre);
    if (okC) {
        pack_w6b<<<32, 256, 0, stream>>>(w_hh, w6);
        lstm_scan_mx6c<<<1, 256, 0, stream>>>(pre, w6, hs);
    } else if (okB) {
        pack_w6b<<<32, 256, 0, stream>>>(w_hh, w6);
        lstm_scan_mx6b<<<1, 256, 0, stream>>>(pre, w6, hs);
    } else {
        lstm_scan_mx8<<<1, 512, 0, stream>>>(pre, w_hh, hs);
    }
    conv_pool<<<128, 256, 0, stream>>>(hs, cw, cb, part);
    final_head<<<1, 128, 0, stream>>>(part, lw, lb, labels, out);
}

// Round 15
// 5111.396 us; speedup vs baseline: 1.0369x; 1.0369x over previous
//
#include <hip/hip_runtime.h>
#include <math.h>

#define T_LEN 8192

typedef float f32x4 __attribute__((ext_vector_type(4)));
typedef int   i32x8 __attribute__((ext_vector_type(8)));
typedef int   i32x6 __attribute__((ext_vector_type(6)));   // fp6 operand tuple

#define DPP_MAX(x, ctrl) fmaxf((x), __int_as_float(__builtin_amdgcn_update_dpp(0, __float_as_int(x), (ctrl), 0xF, 0xF, true)))
#define SB() __builtin_amdgcn_sched_barrier(0)

// LDS-only barrier: drain LDS ops, leave global loads/stores in flight.
#define BAR_LDS() do { \
    __builtin_amdgcn_sched_barrier(0); \
    asm volatile("s_waitcnt lgkmcnt(0)" ::: "memory"); \
    __builtin_amdgcn_s_barrier(); \
    __builtin_amdgcn_sched_barrier(0); \
} while (0)

__device__ __forceinline__ float fexp2(float x) {
#if __has_builtin(__builtin_amdgcn_exp2f)
    return __builtin_amdgcn_exp2f(x);
#else
    return exp2f(x);
#endif
}
__device__ __forceinline__ float rcp1p(float e) {
    return __builtin_amdgcn_rcpf(1.f + e);
}
__device__ __forceinline__ float fsig_c(float x) {
    x = fminf(30.f, fmaxf(-30.f, x));
    float e = __expf(-x);
    return __builtin_amdgcn_rcpf(1.f + e);
}
__device__ __forceinline__ float ftanh_c(float x) {
    x = fminf(15.f, fmaxf(-15.f, x));
    float e = __expf(-2.f * x);
    return (1.f - e) * __builtin_amdgcn_rcpf(1.f + e);
}

// ---- OCP e4m3fn encode ----
__device__ __forceinline__ unsigned char enc_e4m3(float x) {
#if __has_builtin(__builtin_amdgcn_cvt_pk_fp8_f32)
    int v = __builtin_amdgcn_cvt_pk_fp8_f32(x, 0.f, 0, false);
    return (unsigned char)(v & 0xff);
#else
    unsigned u = __float_as_uint(x);
    unsigned s = (u >> 24) & 0x80u;
    float a = fabsf(x);
    if (a > 448.f) a = 448.f;
    if (a < 9.765625e-4f) return (unsigned char)s;
    int e = ((int)((__float_as_uint(a) >> 23) & 0xffu)) - 127;
    int eu = e < -6 ? -6 : e;
    float ulp = exp2f((float)(eu - 3));
    float q = rintf(a / ulp);
    int mant, ee;
    if (eu == -6 && q < 8.f) { mant = (int)q; ee = 0; }
    else {
        if (q >= 16.f) { q *= 0.5f; eu += 1; }
        mant = (int)q - 8; ee = eu + 7;
        if (ee > 15 || (ee == 15 && mant > 6)) { ee = 15; mant = 6; }
    }
    return (unsigned char)(s | (unsigned)(ee << 3) | (unsigned)mant);
#endif
}
__device__ __forceinline__ unsigned pk4(float a, float b, float c, float d) {
    return (unsigned)enc_e4m3(a) | ((unsigned)enc_e4m3(b) << 8)
         | ((unsigned)enc_e4m3(c) << 16) | ((unsigned)enc_e4m3(d) << 24);
}

// ---- OCP e2m3 (fp6) encode: full version (pre-pass only) ----
__device__ __forceinline__ unsigned enc_e2m3(float x) {
    unsigned s = (__float_as_uint(x) >> 31) << 5;
    float a = fabsf(x);
    a = fminf(a, 7.5f);
    if (a < 0.0625f) return s;
    int e = ((int)((__float_as_uint(a) >> 23) & 0xffu)) - 127;
    int eu = e < 0 ? 0 : e;
    float ulp = __int_as_float((unsigned)(eu + 124) << 23);     // 2^(eu-3)
    float q = rintf(a * __builtin_amdgcn_rcpf(ulp));
    int E, M;
    if (e < 0) {
        if (q >= 8.f) { E = 1; M = 0; }
        else { E = 0; M = (int)q; }
    } else {
        if (q >= 16.f) { q = 8.f; eu += 1; }
        if (eu > 2) { E = 3; M = 7; }
        else { E = eu + 1; M = (int)q - 8; }
    }
    return s | (unsigned)(E << 3) | (unsigned)M;
}

// ---- fast e2m3 for |h|<1 (a=4|h|<4): piecewise-linear, bit-identical ----
__device__ __forceinline__ int enc_e2m3_h4(float h) {
    float x = h * 4.f;
    float a = fabsf(x);
    int c1 = (int)rintf(a * 8.f);
    int c2 = (int)rintf(a * 4.f) + 8;
    int mag = (a < 2.f) ? c1 : c2;
    return mag | (int)((__float_as_uint(h) >> 26) & 32u);
}

// ---------------------------------------------------------------------------
// Kernel 0: pre-pass pack for the DPP-quad layout.
// Tile gt, tile-row rw=4kg+g  <->  W_hh row g*256 + 64*(gt>>4) + (gt&15) + 16kg.
// ---------------------------------------------------------------------------
__global__ __launch_bounds__(256) void pack_w6b(
    const float* __restrict__ w_hh,   // (1024, 256)
    unsigned* __restrict__ w6)        // 8192 items x 8 dwords (6 used)
{
    int idx = blockIdx.x * 256 + threadIdx.x;   // 0..8191
    int l  = idx & 63;
    int kt = (idx >> 6) & 1;
    int gt = idx >> 7;                            // 0..63
    int rw = l & 15, ks = l >> 4;
    int orow = ((rw & 3) << 8) + 64 * (gt >> 4) + (gt & 15) + 16 * (rw >> 2);
    const float* s = w_hh + (size_t)orow * 256 + 128 * kt + 32 * ks;
    unsigned d[6] = {0, 0, 0, 0, 0, 0};
#pragma unroll
    for (int j = 0; j < 32; ++j) {
        unsigned c = enc_e2m3(s[j] * 32.f);
        int bit = 6 * j;
        d[bit >> 5] |= c << (bit & 31);
        if ((bit & 31) > 26) d[(bit >> 5) + 1] |= c >> (32 - (bit & 31));
    }
    unsigned* o = w6 + (size_t)idx * 8;
    o[0] = d[0]; o[1] = d[1]; o[2] = d[2];
    o[3] = d[3]; o[4] = d[4]; o[5] = d[5];
    o[6] = 0;    o[7] = 0;
}

// ---------------------------------------------------------------------------
// Kernel 1: pre = relu(embed_W[docs]) @ w_ih^T + (b_ih + b_hh)   (T x 1024)
// Output columns PERMUTED: col' = 4*unit + gate
// ---------------------------------------------------------------------------
__global__ __launch_bounds__(256, 4) void gemm_pre(
    const int* __restrict__ docs,
    const float* __restrict__ embW,
    const float* __restrict__ w_ih,
    const float* __restrict__ b_ih,
    const float* __restrict__ b_hh,
    float* __restrict__ pre)
{
    __shared__ __align__(16) float As[16][68];
    __shared__ __align__(16) float Bs[16][68];
    __shared__ int rowid[64];
    const int bt = blockIdx.x;
    const int bj = blockIdx.y;
    const int tid = threadIdx.x;
    if (tid < 64) rowid[tid] = docs[bt * 64 + tid];
    __syncthreads();
    const int ti = tid & 15, tj = tid >> 4;
    const int r = tid & 63;
    const int kk4 = (tid >> 6) * 4;
    float acc[4][4];
#pragma unroll
    for (int ii = 0; ii < 4; ++ii)
#pragma unroll
        for (int jj = 0; jj < 4; ++jj) acc[ii][jj] = 0.f;

    for (int k0 = 0; k0 < 256; k0 += 16) {
        float4 av = *(const float4*)(embW + (size_t)rowid[r] * 256 + k0 + kk4);
        float4 bv = *(const float4*)(w_ih + (size_t)(bj * 64 + r) * 256 + k0 + kk4);
        As[kk4 + 0][r] = fmaxf(av.x, 0.f);
        As[kk4 + 1][r] = fmaxf(av.y, 0.f);
        As[kk4 + 2][r] = fmaxf(av.z, 0.f);
        As[kk4 + 3][r] = fmaxf(av.w, 0.f);
        Bs[kk4 + 0][r] = bv.x;
        Bs[kk4 + 1][r] = bv.y;
        Bs[kk4 + 2][r] = bv.z;
        Bs[kk4 + 3][r] = bv.w;
        __syncthreads();
#pragma unroll
        for (int kk = 0; kk < 16; ++kk) {
            float4 a = *(const float4*)&As[kk][ti * 4];
            float4 b = *(const float4*)&Bs[kk][tj * 4];
            acc[0][0] += a.x * b.x; acc[0][1] += a.x * b.y; acc[0][2] += a.x * b.z; acc[0][3] += a.x * b.w;
            acc[1][0] += a.y * b.x; acc[1][1] += a.y * b.y; acc[1][2] += a.y * b.z; acc[1][3] += a.y * b.w;
            acc[2][0] += a.z * b.x; acc[2][1] += a.z * b.y; acc[2][2] += a.z * b.z; acc[2][3] += a.z * b.w;
            acc[3][0] += a.w * b.x; acc[3][1] += a.w * b.y; acc[3][2] += a.w * b.z; acc[3][3] += a.w * b.w;
        }
        __syncthreads();
    }
#pragma unroll
    for (int ii = 0; ii < 4; ++ii) {
        int t = bt * 64 + ti * 4 + ii;
#pragma unroll
        for (int jj = 0; jj < 4; ++jj) {
            int j = bj * 64 + tj * 4 + jj;
            int jp = ((j & 255) << 2) | (j >> 8);
            pre[(size_t)t * 1024 + jp] = acc[ii][jj] + b_ih[j] + b_hh[j];
        }
    }
}

// fp6 MFMA dependent pair (kt0 -> kt1), A direct from AGPRs.
#define MFMA_PAIR(RT, DST) \
    asm("v_mfma_scale_f32_16x16x128_f8f6f4 %0, %1, %2, %5, %6, %6 cbsz:2 blgp:2\n\t" \
        "v_mfma_scale_f32_16x16x128_f8f6f4 %0, %3, %4, %0, %6, %6 cbsz:2 blgp:2" \
        : "=&v"(DST) \
        : "a"(wA[RT][0]), "v"(bq0), "a"(wA[RT][1]), "v"(bq1), "v"(CZ), "v"(sc))

// ---------------------------------------------------------------------------
// Kernel 2a (primary): 8-wave (2/SIMD) MX-fp6 scan. Per-SIMD MFMA pipe work
// unchanged (32 MFMAs = ~704 cy) but the two waves on each SIMD overlap: one
// wave's VALU tail runs while the other's MFMAs occupy the matrix pipe.
// Wave w owns tiles gt=8w..8w+7; lane l (l&15<8) owns unit
// u = 64*(w>>1) + 8*(w&1) + (l&15) + 16*(l>>4). pack_w6b layout unchanged.
// ---------------------------------------------------------------------------
__global__ __launch_bounds__(512, 2) void lstm_scan_mx6d(
    const float* __restrict__ pre,    // (T, 1024), permuted cols 4u+gate
    const unsigned* __restrict__ w6,  // packed fp6 weights (pack_w6b layout)
    float* __restrict__ hs)           // (T, 256) fp32
{
    const int tid = threadIdx.x;
    const int w  = tid >> 6;          // wave 0..7
    const int l  = tid & 63;
    const int rto = l & 15;           // tile select (owners: rto<8)
    const int kgr = l >> 4;           // B k-slice / unit sub-index
    const float C_L2E  = -1.4426950408889634f;
    const float C_L2E2 = -2.8853900817779268f;
    const float I_L2E  = C_L2E  / 128.f;
    const float I_L2E2 = C_L2E2 / 128.f;

    __shared__ __align__(32) unsigned char h6pk[2][256];  // 8 windows x 32B

    // ---- weights: 8 tiles x 2 kt as 6-dword fp6 tuples (AGPR-resident) ----
    i32x6 wA[8][2];
#pragma unroll
    for (int rtt = 0; rtt < 8; ++rtt) {
#pragma unroll
        for (int kt = 0; kt < 2; ++kt) {
            int gt = 8 * w + rtt;
            const unsigned* s = w6 + (size_t)((gt * 2 + kt) * 64 + l) * 8;
            uint4 lo = *(const uint4*)s;
            uint2 hi = *(const uint2*)(s + 4);
            i32x6 v;
            v[0] = (int)lo.x; v[1] = (int)lo.y; v[2] = (int)lo.z;
            v[3] = (int)lo.w; v[4] = (int)hi.x; v[5] = (int)hi.y;
            wA[rtt][kt] = v;
        }
    }

    for (int i = tid; i < 512; i += 512) ((unsigned char*)h6pk)[i] = 0;

    const bool isown = (rto < 8);
    const int u = 64 * (w >> 1) + 8 * (w & 1) + (rto & 7) + 16 * kgr;  // owned unit
    float c_st = 0.f;

    const bool b0 = (rto & 1), b1 = (rto & 2), b2 = (rto & 4);

    // DPP-quad pack: owner quads have (l&8)==0; quad covers 4 consecutive units
    const int qi  = l & 3;
    const bool iswr = ((l & 8) == 0) && (qi < 3);
    const int rsh = 2 * qi;
    const int wofs = (u >> 5) * 32 + 3 * ((u & 31) >> 2) + qi;

    f32x4 CZ = (f32x4){0.f, 0.f, 0.f, 0.f};
    asm("" : "+v"(CZ));                                   // pin zero tuple
    int sc = 0x7f7f7f7f;                                  // e8m0 scale = 1.0

    f32x4 p4c = *(const f32x4*)(pre + 4 * u);             // t = 0
    float tx = p4c.x * C_L2E;
    float ty = p4c.y * C_L2E;
    float tz = p4c.z * C_L2E2;
    float tw = p4c.w * C_L2E;
    const float* pp = pre + 1024 + 4 * u;
    float* hsp = hs + u;
    const unsigned char* h6base = (const unsigned char*)h6pk;
    BAR_LDS();

#define LSTM_STEP(RD, WR) do { \
    f32x4 p4n = *(const f32x4*)pp; pp += 1024; \
    i32x6 bq0, bq1; \
    { \
        const unsigned char* bp0 = h6base + (RD) + kgr * 32; \
        uint4 lo = *(const uint4*)bp0; \
        uint2 hi = *(const uint2*)(bp0 + 16); \
        bq0[0] = (int)lo.x; bq0[1] = (int)lo.y; bq0[2] = (int)lo.z; \
        bq0[3] = (int)lo.w; bq0[4] = (int)hi.x; bq0[5] = (int)hi.y; \
        const unsigned char* bp1 = bp0 + 128; \
        uint4 lo1 = *(const uint4*)bp1; \
        uint2 hi1 = *(const uint2*)(bp1 + 16); \
        bq1[0] = (int)lo1.x; bq1[1] = (int)lo1.y; bq1[2] = (int)lo1.z; \
        bq1[3] = (int)lo1.w; bq1[4] = (int)hi1.x; bq1[5] = (int)hi1.y; \
    } \
    f32x4 a0, a1, a2, a3, a4, a5, a6, a7; \
    MFMA_PAIR(0, a0);  MFMA_PAIR(1, a1);  MFMA_PAIR(2, a2);  MFMA_PAIR(3, a3); \
    SB(); \
    f32x4 s0 = b0 ? a1 : a0; \
    MFMA_PAIR(4, a4);  MFMA_PAIR(5, a5);  SB(); \
    f32x4 s1 = b0 ? a3 : a2; \
    MFMA_PAIR(6, a6);  MFMA_PAIR(7, a7);  SB(); \
    f32x4 s2 = b0 ? a5 : a4; \
    f32x4 q0 = b1 ? s1 : s0; \
    asm volatile("s_nop 7\n\ts_nop 7" : "+v"(a6), "+v"(a7)); \
    f32x4 s3 = b0 ? a7 : a6; \
    f32x4 q1 = b1 ? s3 : s2; \
    f32x4 av = b2 ? q1 : q0; \
    float nx = p4n.x * C_L2E, ny = p4n.y * C_L2E; \
    float nz = p4n.z * C_L2E2, nw = p4n.w * C_L2E; \
    float si = rcp1p(fexp2(fmaf(av.x, I_L2E,  tx))); \
    float sf = rcp1p(fexp2(fmaf(av.y, I_L2E,  ty))); \
    float tg = 2.f * rcp1p(fexp2(fmaf(av.z, I_L2E2, tz))) - 1.f; \
    float so = rcp1p(fexp2(fmaf(av.w, I_L2E,  tw))); \
    c_st = sf * c_st + si * tg; \
    float h = so * (2.f * rcp1p(fexp2(c_st * C_L2E2)) - 1.f); \
    if (isown) hsp[0] = h; \
    hsp += 256; \
    int code = enc_e2m3_h4(h); \
    int cnx = __builtin_amdgcn_update_dpp(0, code, 0x39, 0xF, 0xF, true); \
    if (iswr) { \
        unsigned byte = (((unsigned)code >> rsh) | ((unsigned)cnx << (6 - rsh))) & 0xffu; \
        *((unsigned char*)h6pk + (WR) + wofs) = (unsigned char)byte; \
    } \
    tx = nx; ty = ny; tz = nz; tw = nw; \
    BAR_LDS(); \
} while (0)

    for (int t2 = 0; t2 < T_LEN; t2 += 2) {
        LSTM_STEP(256, 0);    // even step: read parity 1, write parity 0
        LSTM_STEP(0, 256);    // odd step: read parity 0, write parity 1
    }
#undef LSTM_STEP
}

// legacy dependent pair over 16-tile array (fallback kernel mx6b)
#define MFMA_PAIR16(RT, DST) \
    asm("v_mfma_scale_f32_16x16x128_f8f6f4 %0, %1, %2, %5, %6, %6 cbsz:2 blgp:2\n\t" \
        "v_mfma_scale_f32_16x16x128_f8f6f4 %0, %3, %4, %0, %6, %6 cbsz:2 blgp:2" \
        : "=&v"(DST) \
        : "a"(wB[RT][0]), "v"(bq0), "a"(wB[RT][1]), "v"(bq1), "v"(CZ), "v"(sc))

// ---------------------------------------------------------------------------
// Kernel 2b (fallback 1): r13 proven 4-wave kernel (4848 us).
// ---------------------------------------------------------------------------
__global__ __launch_bounds__(256, 1) void lstm_scan_mx6b(
    const float* __restrict__ pre,
    const unsigned* __restrict__ w6,
    float* __restrict__ hs)
{
    const int tid = threadIdx.x;
    const int w  = tid >> 6;
    const int l  = tid & 63;
    const int rto = l & 15;
    const int kgr = l >> 4;
    const float C_L2E  = -1.4426950408889634f;
    const float C_L2E2 = -2.8853900817779268f;
    const float I_L2E  = C_L2E  / 128.f;
    const float I_L2E2 = C_L2E2 / 128.f;

    __shared__ __align__(32) unsigned char h6pk[2][256];

    i32x6 wB[16][2];
#pragma unroll
    for (int rtt = 0; rtt < 16; ++rtt) {
#pragma unroll
        for (int kt = 0; kt < 2; ++kt) {
            int gt = 16 * w + rtt;
            const unsigned* s = w6 + (size_t)((gt * 2 + kt) * 64 + l) * 8;
            uint4 lo = *(const uint4*)s;
            uint2 hi = *(const uint2*)(s + 4);
            i32x6 v;
            v[0] = (int)lo.x; v[1] = (int)lo.y; v[2] = (int)lo.z;
            v[3] = (int)lo.w; v[4] = (int)hi.x; v[5] = (int)hi.y;
            wB[rtt][kt] = v;
        }
    }

    for (int i = tid; i < 512; i += 256) ((unsigned char*)h6pk)[i] = 0;

    const int u = 64 * w + rto + 16 * kgr;
    float c_st = 0.f;

    const bool b0 = (rto & 1), b1 = (rto & 2), b2 = (rto & 4), b3 = (rto & 8);

    const int qi  = l & 3;
    const bool iswr = (qi < 3);
    const int rsh = 2 * qi;
    const int qq  = l >> 2;
    const int G   = 4 * (qq >> 2) + (qq & 3);
    const int wofs = (2 * w + (G >> 3)) * 32 + 3 * (G & 7) + qi;

    f32x4 CZ = (f32x4){0.f, 0.f, 0.f, 0.f};
    asm("" : "+v"(CZ));
    int sc = 0x7f7f7f7f;

    f32x4 p4c = *(const f32x4*)(pre + 4 * u);
    float tx = p4c.x * C_L2E;
    float ty = p4c.y * C_L2E;
    float tz = p4c.z * C_L2E2;
    float tw = p4c.w * C_L2E;
    const float* pp = pre + 1024 + 4 * u;
    float* hsp = hs + u;
    const unsigned char* h6base = (const unsigned char*)h6pk;
    BAR_LDS();

#define LSTM_STEP(RD, WR) do { \
    f32x4 p4n = *(const f32x4*)pp; pp += 1024; \
    i32x6 bq0, bq1; \
    { \
        const unsigned char* bp0 = h6base + (RD) + kgr * 32; \
        uint4 lo = *(const uint4*)bp0; \
        uint2 hi = *(const uint2*)(bp0 + 16); \
        bq0[0] = (int)lo.x; bq0[1] = (int)lo.y; bq0[2] = (int)lo.z; \
        bq0[3] = (int)lo.w; bq0[4] = (int)hi.x; bq0[5] = (int)hi.y; \
        const unsigned char* bp1 = bp0 + 128; \
        uint4 lo1 = *(const uint4*)bp1; \
        uint2 hi1 = *(const uint2*)(bp1 + 16); \
        bq1[0] = (int)lo1.x; bq1[1] = (int)lo1.y; bq1[2] = (int)lo1.z; \
        bq1[3] = (int)lo1.w; bq1[4] = (int)hi1.x; bq1[5] = (int)hi1.y; \
    } \
    f32x4 a0, a1, a2, a3, a4, a5, a6, a7, a8, a9, a10, a11, a12, a13, a14, a15; \
    MFMA_PAIR16(0, a0);  MFMA_PAIR16(1, a1);  MFMA_PAIR16(2, a2);  MFMA_PAIR16(3, a3); \
    SB(); \
    f32x4 s0 = b0 ? a1 : a0; \
    MFMA_PAIR16(4, a4);  MFMA_PAIR16(5, a5);  SB(); \
    f32x4 s1 = b0 ? a3 : a2; \
    MFMA_PAIR16(6, a6);  MFMA_PAIR16(7, a7);  SB(); \
    f32x4 s2 = b0 ? a5 : a4; \
    MFMA_PAIR16(8, a8);  MFMA_PAIR16(9, a9);  SB(); \
    f32x4 s3 = b0 ? a7 : a6; \
    f32x4 q0 = b1 ? s1 : s0; \
    MFMA_PAIR16(10, a10); MFMA_PAIR16(11, a11); SB(); \
    f32x4 s4 = b0 ? a9 : a8; \
    MFMA_PAIR16(12, a12); MFMA_PAIR16(13, a13); SB(); \
    f32x4 s5 = b0 ? a11 : a10; \
    f32x4 q1 = b1 ? s3 : s2; \
    MFMA_PAIR16(14, a14); MFMA_PAIR16(15, a15); SB(); \
    f32x4 s6 = b0 ? a13 : a12; \
    asm volatile("s_nop 7\n\ts_nop 7" : "+v"(a14), "+v"(a15)); \
    f32x4 s7 = b0 ? a15 : a14; \
    f32x4 q2 = b1 ? s5 : s4; \
    f32x4 q3 = b1 ? s7 : s6; \
    f32x4 r0 = b2 ? q1 : q0; \
    f32x4 r1 = b2 ? q3 : q2; \
    f32x4 av = b3 ? r1 : r0; \
    float nx = p4n.x * C_L2E, ny = p4n.y * C_L2E; \
    float nz = p4n.z * C_L2E2, nw = p4n.w * C_L2E; \
    float si = rcp1p(fexp2(fmaf(av.x, I_L2E,  tx))); \
    float sf = rcp1p(fexp2(fmaf(av.y, I_L2E,  ty))); \
    float tg = 2.f * rcp1p(fexp2(fmaf(av.z, I_L2E2, tz))) - 1.f; \
    float so = rcp1p(fexp2(fmaf(av.w, I_L2E,  tw))); \
    c_st = sf * c_st + si * tg; \
    float h = so * (2.f * rcp1p(fexp2(c_st * C_L2E2)) - 1.f); \
    hsp[0] = h; hsp += 256; \
    int code = enc_e2m3_h4(h); \
    int cnx = __builtin_amdgcn_update_dpp(0, code, 0x39, 0xF, 0xF, true); \
    if (iswr) { \
        unsigned byte = (((unsigned)code >> rsh) | ((unsigned)cnx << (6 - rsh))) & 0xffu; \
        *((unsigned char*)h6pk + (WR) + wofs) = (unsigned char)byte; \
    } \
    tx = nx; ty = ny; tz = nz; tw = nw; \
    BAR_LDS(); \
} while (0)

    for (int t2 = 0; t2 < T_LEN; t2 += 2) {
        LSTM_STEP(256, 0);
        LSTM_STEP(0, 256);
    }
#undef LSTM_STEP
}

// ---------------------------------------------------------------------------
// Kernel 2c (fallback 2): round-6 proven MX-fp8 scan.
// ---------------------------------------------------------------------------
__global__ __launch_bounds__(512, 2) void lstm_scan_mx8(
    const float* __restrict__ pre,
    const float* __restrict__ w_hh,
    float* __restrict__ hs)
{
    const int tid = threadIdx.x;
    const int w  = tid >> 6;
    const int l  = tid & 63;
    const int rw = l & 15;
    const int kg = l >> 4;
    const float INV = 1.f / 32768.f;

    __shared__ __align__(16) unsigned char h8[2 * 256];
    __shared__ __align__(16) float ldsPre[2][1024];

    i32x8 wA[8][2];
#pragma unroll
    for (int rt = 0; rt < 8; ++rt) {
#pragma unroll
        for (int kt = 0; kt < 2; ++kt) {
            int rowp = ((8 * w + rt) << 4) + rw;
            int orow = ((rowp & 3) << 8) + (rowp >> 2);
            const float* s = w_hh + (size_t)orow * 256 + 128 * kt + 32 * kg;
            i32x8 v;
#pragma unroll
            for (int d = 0; d < 8; ++d) {
                float4 f = *(const float4*)(s + 4 * d);
                v[d] = (int)pk4(f.x * 512.f, f.y * 512.f, f.z * 512.f, f.w * 512.f);
            }
            wA[rt][kt] = v;
        }
    }

    for (int i = tid; i < 512; i += 512) h8[i] = 0;
    {
        float2 p = *(const float2*)(pre + 2 * tid);
        *(float2*)&ldsPre[0][2 * tid] = p;
    }
    float c_st = 0.f;
    const bool isup = (rw < 8);
    const int u = 32 * w + 4 * (rw & 7) + kg;
    const float* pnext = pre + 1024 + 2 * tid;
    float* hsp = hs + u;
    __syncthreads();

    for (int t = 0; t < T_LEN; ++t) {
        const int PW = t & 1;
        const int PR = PW ^ 1;

        f32x4 p4 = *(const f32x4*)&ldsPre[PW][4 * u];

        float2 pv = *(const float2*)pnext;
        if (t + 2 < T_LEN) pnext += 1024;

        i32x8 bq[2];
#pragma unroll
        for (int kt = 0; kt < 2; ++kt) {
            const unsigned char* bp = &h8[PR * 256 + 128 * kt + 32 * kg];
            uint4 lo = *(const uint4*)bp;
            uint4 hi = *(const uint4*)(bp + 16);
            i32x8 b;
            b[0] = (int)lo.x; b[1] = (int)lo.y; b[2] = (int)lo.z; b[3] = (int)lo.w;
            b[4] = (int)hi.x; b[5] = (int)hi.y; b[6] = (int)hi.z; b[7] = (int)hi.w;
            bq[kt] = b;
        }

        f32x4 acc[8];
#pragma unroll
        for (int rt = 0; rt < 8; ++rt) acc[rt] = (f32x4){0.f, 0.f, 0.f, 0.f};
#pragma unroll
        for (int rt = 0; rt < 8; ++rt)
#pragma unroll
            for (int kt = 0; kt < 2; ++kt)
                acc[rt] = __builtin_amdgcn_mfma_scale_f32_16x16x128_f8f6f4(
                    wA[rt][kt], bq[kt], acc[rt],
                    0, 0, 0, 0x7f7f7f7f, 0, 0x7f7f7f7f);

        if (isup) {
            f32x4 av = acc[0];
            av = (rw == 1) ? acc[1] : av;
            av = (rw == 2) ? acc[2] : av;
            av = (rw == 3) ? acc[3] : av;
            av = (rw == 4) ? acc[4] : av;
            av = (rw == 5) ? acc[5] : av;
            av = (rw == 6) ? acc[6] : av;
            av = (rw == 7) ? acc[7] : av;
            float gi = fmaf(av.x, INV, p4.x);
            float gf = fmaf(av.y, INV, p4.y);
            float gg = fmaf(av.z, INV, p4.z);
            float go = fmaf(av.w, INV, p4.w);
            float si = fsig_c(gi);
            float sf = fsig_c(gf);
            float tg = ftanh_c(gg);
            float so = fsig_c(go);
            c_st = sf * c_st + si * tg;
            float h = so * ftanh_c(c_st);
            hsp[0] = h;
            h8[PW * 256 + u] = enc_e4m3(h * 64.f);
        }
        hsp += 256;

        *(float2*)&ldsPre[PR][2 * tid] = pv;

        __syncthreads();
    }
}

// ---------------------------------------------------------------------------
// Kernel 3: conv (FN=128, FL=5) over hs + per-block max over its 64 t's.
// ---------------------------------------------------------------------------
__global__ __launch_bounds__(256) void conv_pool(
    const float* __restrict__ hs,
    const float* __restrict__ cw,
    const float* __restrict__ cb,
    float* __restrict__ part)
{
    __shared__ __align__(16) float hst[68 * 260];
    __shared__ __align__(16) float cwS[128 * 68];
    const int blk = blockIdx.x;
    const int t0 = blk * 64;
    const int tid = threadIdx.x;
    const int i = tid & 15;
    const int g = tid >> 4;

    for (int e = tid; e < 68 * 64; e += 256) {
        int rr = e >> 6;
        int c4 = (e & 63) * 4;
        int tg = t0 + rr; if (tg > 8191) tg = 8191;
        float4 v = *(const float4*)(hs + (size_t)tg * 256 + c4);
        *(float4*)&hst[rr * 260 + c4] = v;
    }

    float acc[4][8];
#pragma unroll
    for (int tt = 0; tt < 4; ++tt)
#pragma unroll
        for (int j = 0; j < 8; ++j) acc[tt][j] = 0.f;

    for (int l = 0; l < 5; ++l) {
        for (int hc = 0; hc < 4; ++hc) {
            __syncthreads();
            {
                int n = tid >> 1;
                int hb = (tid & 1) * 32;
                const float* src = cw + (size_t)n * 1280 + l * 256 + hc * 64 + hb;
                float* dst = &cwS[n * 68 + hb];
#pragma unroll
                for (int q = 0; q < 8; ++q) {
                    float4 v = *(const float4*)(src + 4 * q);
                    *(float4*)(dst + 4 * q) = v;
                }
            }
            __syncthreads();
#pragma unroll 4
            for (int q = 0; q < 16; ++q) {
                float4 hvv[4];
#pragma unroll
                for (int tt = 0; tt < 4; ++tt)
                    hvv[tt] = *(const float4*)&hst[(i + 16 * tt + l) * 260 + hc * 64 + 4 * q];
#pragma unroll
                for (int j = 0; j < 8; ++j) {
                    float4 wv = *(const float4*)&cwS[(g + 16 * j) * 68 + 4 * q];
#pragma unroll
                    for (int tt = 0; tt < 4; ++tt) {
                        acc[tt][j] += hvv[tt].x * wv.x + hvv[tt].y * wv.y
                                    + hvv[tt].z * wv.z + hvv[tt].w * wv.w;
                    }
                }
            }
        }
    }

    float m[8];
#pragma unroll
    for (int j = 0; j < 8; ++j) {
        int n = g + 16 * j;
        float cbn = cb[n];
        float mm = -INFINITY;
#pragma unroll
        for (int tt = 0; tt < 4; ++tt) {
            int t = t0 + i + 16 * tt;
            float v = acc[tt][j] + cbn;
            if (t < 8188) mm = fmaxf(mm, v);
        }
        mm = DPP_MAX(mm, 0xB1);
        mm = DPP_MAX(mm, 0x4E);
        mm = DPP_MAX(mm, 0x141);
        mm = DPP_MAX(mm, 0x140);
        m[j] = mm;
    }
    if (i == 0) {
#pragma unroll
        for (int j = 0; j < 8; ++j)
            part[(size_t)blk * 128 + g + 16 * j] = m[j];
    }
}

// ---------------------------------------------------------------------------
// Kernel 4: final head — pool-reduce, logits, log_softmax, loss + acc.
// ---------------------------------------------------------------------------
__global__ void final_head(
    const float* __restrict__ part,
    const float* __restrict__ logits_w,
    const float* __restrict__ logits_b,
    const int* __restrict__ labels,
    float* __restrict__ out)
{
    __shared__ float pooled[128];
    __shared__ float lgt[20];
    int tid = threadIdx.x;
    float mx = -INFINITY;
    for (int b = 0; b < 128; ++b) mx = fmaxf(mx, part[(size_t)b * 128 + tid]);
    pooled[tid] = mx;
    __syncthreads();
    if (tid < 20) {
        float s = logits_b[tid];
        for (int k = 0; k < 128; ++k) s += logits_w[tid * 128 + k] * pooled[k];
        lgt[tid] = s;
    }
    __syncthreads();
    if (tid == 0) {
        float m = lgt[0]; int am = 0;
        for (int c2 = 1; c2 < 20; ++c2) { if (lgt[c2] > m) { m = lgt[c2]; am = c2; } }
        float se = 0.f;
        for (int c2 = 0; c2 < 20; ++c2) se += expf(lgt[c2] - m);
        float lse = m + logf(se);
        int lbl = labels[0];
        out[0] = -(lgt[lbl] - lse);
        out[1] = (am == lbl) ? 1.f : 0.f;
    }
}

// ---------------------------------------------------------------------------
extern "C" void kernel_launch(void* const* d_in, const int* in_sizes, int n_in,
                              void* d_out, int out_size, void* d_ws, size_t ws_size,
                              hipStream_t stream) {
    (void)in_sizes; (void)n_in; (void)out_size;
    const int*   docs   = (const int*)d_in[0];
    const int*   labels = (const int*)d_in[2];
    const float* embW   = (const float*)d_in[4];
    const float* w_ih   = (const float*)d_in[5];
    const float* w_hh   = (const float*)d_in[6];
    const float* b_ih   = (const float*)d_in[7];
    const float* b_hh   = (const float*)d_in[8];
    const float* cw     = (const float*)d_in[9];
    const float* cb     = (const float*)d_in[10];
    const float* lw     = (const float*)d_in[11];
    const float* lb     = (const float*)d_in[12];
    float* out = (float*)d_out;

    char* ws = (char*)d_ws;
    float*    pre  = (float*)(ws);                 // 33554432 B
    float*    hs   = (float*)(ws + 33554432);      //  8388608 B
    float*    part = (float*)(ws + 41943040);      //    65536 B
    unsigned* w6   = (unsigned*)(ws + 42008576);   //   262144 B

    bool ws_ok = (ws_size >= (size_t)42270720);
    hipFuncAttributes aD, aB;
    bool okD = ws_ok
        && (hipFuncGetAttributes(&aD, (const void*)lstm_scan_mx6d) == hipSuccess)
        && (aD.localSizeBytes == 0);
    bool okB = ws_ok
        && (hipFuncGetAttributes(&aB, (const void*)lstm_scan_mx6b) == hipSuccess)
        && (aB.localSizeBytes == 0);

    gemm_pre<<<dim3(128, 16, 1), 256, 0, stream>>>(docs, embW, w_ih, b_ih, b_hh, pre);
    if (okD) {
        pack_w6b<<<32, 256, 0, stream>>>(w_hh, w6);
        lstm_scan_mx6d<<<1, 512, 0, stream>>>(pre, w6, hs);
    } else if (okB) {
        pack_w6b<<<32, 256, 0, stream>>>(w_hh, w6);
        lstm_scan_mx6b<<<1, 256, 0, stream>>>(pre, w6, hs);
    } else {
        lstm_scan_mx8<<<1, 512, 0, stream>>>(pre, w_hh, hs);
    }
    conv_pool<<<128, 256, 0, stream>>>(hs, cw, cb, part);
    final_head<<<1, 128, 0, stream>>>(part, lw, lb, labels, out);
}